// Round 1
// baseline (451.771 us; speedup 1.0000x reference)
//
#include <hip/hip_runtime.h>
#include <cstdint>
#include <cstddef>

#define B_SZ 16384
#define DIN  1024
#define DOUT 1024
#define SPLITK 8

typedef short bf16x8 __attribute__((ext_vector_type(8)));
typedef float f32x4  __attribute__((ext_vector_type(4)));

static __device__ __forceinline__ short f2bf(float f) {
    union { float f; unsigned u; } v; v.f = f;
    unsigned r = v.u + 0x7fffu + ((v.u >> 16) & 1u);
    return (short)(r >> 16);
}
static __device__ __forceinline__ float bf2f(short s) {
    union { unsigned u; float f; } v; v.u = ((unsigned)(unsigned short)s) << 16;
    return v.f;
}
// async global->LDS, 16B per lane; LDS dest is wave-uniform base + lane*16
static __device__ __forceinline__ void gload_lds16(const short* g, short* l) {
    __builtin_amdgcn_global_load_lds(
        (const __attribute__((address_space(1))) void*)g,
        (__attribute__((address_space(3))) void*)l, 16, 0, 0);
}

// ---------------- fp32 -> bf16 convert (for weights) ----------------
__global__ __launch_bounds__(256) void convert_f32_bf16(const float* __restrict__ in,
                                                        short* __restrict__ out, int n4) {
    int i = blockIdx.x * 256 + threadIdx.x;
    if (i < n4) {
        float4 v = ((const float4*)in)[i];
        short4 o;
        o.x = f2bf(v.x); o.y = f2bf(v.y); o.z = f2bf(v.z); o.w = f2bf(v.w);
        ((short4*)out)[i] = o;
    }
}

// ---------------- x: fp32 [B,DIN] -> xb bf16 [B,DIN] + xT bf16 [DIN,B] ----------------
__global__ __launch_bounds__(256) void x_convert(const float* __restrict__ x,
                                                 short* __restrict__ xb,
                                                 short* __restrict__ xT) {
    __shared__ short t[64 * 72];
    const int b0 = blockIdx.x * 64;
    const int d0 = blockIdx.y * 64;
    const int tid = threadIdx.x;
    const int r = tid >> 2;            // batch row 0..63
    const int c = (tid & 3) * 16;      // col seg
    short loc[16];
    #pragma unroll
    for (int i = 0; i < 4; ++i) {
        float4 v = *(const float4*)&x[(size_t)(b0 + r) * DIN + d0 + c + i * 4];
        loc[i * 4 + 0] = f2bf(v.x); loc[i * 4 + 1] = f2bf(v.y);
        loc[i * 4 + 2] = f2bf(v.z); loc[i * 4 + 3] = f2bf(v.w);
    }
    *(bf16x8*)&xb[(size_t)(b0 + r) * DIN + d0 + c]     = *(bf16x8*)&loc[0];
    *(bf16x8*)&xb[(size_t)(b0 + r) * DIN + d0 + c + 8] = *(bf16x8*)&loc[8];
    #pragma unroll
    for (int i = 0; i < 16; ++i) t[(c + i) * 72 + r] = loc[i];
    __syncthreads();
    const int d = tid >> 2, bs = (tid & 3) * 16;
    *(bf16x8*)&xT[(size_t)(d0 + d) * B_SZ + b0 + bs]     = *(bf16x8*)&t[d * 72 + bs];
    *(bf16x8*)&xT[(size_t)(d0 + d) * B_SZ + b0 + bs + 8] = *(bf16x8*)&t[d * 72 + bs + 8];
}

// ---------------- LEGACY: fast fp32 [B,DOUT] -> fastT bf16 [DOUT,B] ----------------
__global__ __launch_bounds__(256) void fast_trans(const float* __restrict__ fast,
                                                  short* __restrict__ fastT) {
    __shared__ short t[64 * 72];
    const int b0 = blockIdx.x * 64;
    const int d0 = blockIdx.y * 64;
    const int tid = threadIdx.x;
    const int r = tid >> 2;
    const int c = (tid & 3) * 16;
    short loc[16];
    #pragma unroll
    for (int i = 0; i < 4; ++i) {
        float4 v = *(const float4*)&fast[(size_t)(b0 + r) * DOUT + d0 + c + i * 4];
        loc[i * 4 + 0] = f2bf(v.x); loc[i * 4 + 1] = f2bf(v.y);
        loc[i * 4 + 2] = f2bf(v.z); loc[i * 4 + 3] = f2bf(v.w);
    }
    #pragma unroll
    for (int i = 0; i < 16; ++i) t[(c + i) * 72 + r] = loc[i];
    __syncthreads();
    const int d = tid >> 2, bs = (tid & 3) * 16;
    *(bf16x8*)&fastT[(size_t)(d0 + d) * B_SZ + b0 + bs]     = *(bf16x8*)&t[d * 72 + bs];
    *(bf16x8*)&fastT[(size_t)(d0 + d) * B_SZ + b0 + bs + 8] = *(bf16x8*)&t[d * 72 + bs + 8];
}

// ---------------- init: eff_lr + zero csq ----------------
__global__ __launch_bounds__(256) void init_kernel(const float* __restrict__ plast,
                                                   float* __restrict__ eff_lr,
                                                   float* __restrict__ csq) {
    int tid = threadIdx.x;
    // zero csq (needed by fused-path atomics; harmless in legacy path)
    for (int i = tid; i < DOUT; i += 256) csq[i] = 0.f;
    float s = 0.f;
    for (int i = tid; i < B_SZ; i += 256) s += plast[i];
    __shared__ float red[256];
    red[tid] = s; __syncthreads();
    for (int off = 128; off > 0; off >>= 1) {
        if (tid < off) red[tid] += red[tid + off];
        __syncthreads();
    }
    if (tid == 0) eff_lr[0] = (red[0] / (float)B_SZ) * 0.1f;
}

// ---------------- LEGACY dual GEMM (m97 structure): C[B,2048] = xb @ wcat^T ----------------
__global__ __launch_bounds__(256) void dual_gemm(
    const short* __restrict__ Xb,    // [B, DIN]
    const short* __restrict__ Wc,    // [2048, DIN]
    float* __restrict__ slow_out,    // [B, 1024]
    float* __restrict__ fast_out)    // [B, 1024]
{
    __shared__ short lA[128 * 32];
    __shared__ short lB[128 * 32];
    const int tid = threadIdx.x;
    const int lane = tid & 63;
    const int wave = tid >> 6;
    const int wm = wave & 1, wn = wave >> 1;
    const int quad = lane >> 4, l16 = lane & 15;
    const int m0 = blockIdx.x * 128;
    const int n0 = blockIdx.y * 128;
    const int lrow = lane >> 2;
    const int lcol = (lane & 3) * 8;

    f32x4 acc[4][4] = {};

    const short* gA0 = &Xb[(size_t)(m0 + wave * 32 + lrow) * DIN + lcol];
    const short* gA1 = gA0 + (size_t)16 * DIN;
    const short* gB0 = &Wc[(size_t)(n0 + wave * 32 + lrow) * DIN + lcol];
    const short* gB1 = gB0 + (size_t)16 * DIN;
    short* sA0 = &lA[(wave * 32) * 32];
    short* sA1 = &lA[(wave * 32 + 16) * 32];
    short* sB0 = &lB[(wave * 32) * 32];
    short* sB1 = &lB[(wave * 32 + 16) * 32];

    for (int k0 = 0; k0 < DIN; k0 += 32) {
        gload_lds16(gA0 + k0, sA0);
        gload_lds16(gA1 + k0, sA1);
        gload_lds16(gB0 + k0, sB0);
        gload_lds16(gB1 + k0, sB1);
        __syncthreads();
        bf16x8 af[4], bfr[4];
        #pragma unroll
        for (int t = 0; t < 4; ++t) {
            af[t]  = *(const bf16x8*)&lA[(wm * 64 + t * 16 + l16) * 32 + quad * 8];
            bfr[t] = *(const bf16x8*)&lB[(wn * 64 + t * 16 + l16) * 32 + quad * 8];
        }
        #pragma unroll
        for (int tm = 0; tm < 4; ++tm)
            #pragma unroll
            for (int tn = 0; tn < 4; ++tn)
                acc[tm][tn] = __builtin_amdgcn_mfma_f32_16x16x32_bf16(af[tm], bfr[tn], acc[tm][tn], 0, 0, 0);
        __syncthreads();
    }
    float* dst = (n0 < 1024) ? slow_out : fast_out;
    const int cb = (n0 < 1024) ? n0 : n0 - 1024;
    #pragma unroll
    for (int tm = 0; tm < 4; ++tm) {
        int r0 = m0 + wm * 64 + tm * 16 + quad * 4;
        #pragma unroll
        for (int tn = 0; tn < 4; ++tn) {
            int cc = cb + wn * 64 + tn * 16 + l16;
            #pragma unroll
            for (int r = 0; r < 4; ++r)
                dst[(size_t)(r0 + r) * 1024 + cc] = acc[tm][tn][r];
        }
    }
}

// ---------------- FUSED dual GEMM: per block, 128 rows x 64 cols of BOTH slow & fast ----
// Same inner-loop profile as legacy (4 gload_lds16 + 16 MFMA per K-step, 16 KB LDS).
// B staging is stacked: lB rows 0..63 = Ws cols [n0,n0+64), rows 64..127 = Wf same cols.
// Epilogue: slow fp32, combined = slow + alpha*fast fp32, fastT bf16 (short4 along m),
// and csq partial sums via quad-shuffle + atomicAdd.
__global__ __launch_bounds__(256) void dual_gemm_fused(
    const short* __restrict__ Xb,    // [B, DIN]
    const short* __restrict__ Wc,    // [2048, DIN]
    float* __restrict__ slow_out,    // [B, 1024]
    float* __restrict__ comb_out,    // [B, 1024]
    short* __restrict__ fastT,       // [1024, B]
    float* __restrict__ csq,         // [1024], pre-zeroed
    const float* __restrict__ alpha)
{
    __shared__ short lA[128 * 32];
    __shared__ short lB[128 * 32];
    const int tid = threadIdx.x;
    const int lane = tid & 63;
    const int wave = tid >> 6;
    const int wm = wave & 1, wn = wave >> 1;
    const int quad = lane >> 4, l16 = lane & 15;
    const int m0 = blockIdx.x * 128;
    const int n0 = blockIdx.y * 64;
    const int lrow = lane >> 2;
    const int lcol = (lane & 3) * 8;

    f32x4 accS[4][2] = {};
    f32x4 accF[4][2] = {};

    const short* gA0 = &Xb[(size_t)(m0 + wave * 32 + lrow) * DIN + lcol];
    const short* gA1 = gA0 + (size_t)16 * DIN;
    // waves 0,1 stage Ws rows; waves 2,3 stage Wf rows (offset +1024 in Wc)
    const int brow = (wave < 2) ? (n0 + wave * 32 + lrow)
                                : (1024 + n0 + (wave - 2) * 32 + lrow);
    const short* gB0 = &Wc[(size_t)brow * DIN + lcol];
    const short* gB1 = gB0 + (size_t)16 * DIN;
    short* sA0 = &lA[(wave * 32) * 32];
    short* sA1 = &lA[(wave * 32 + 16) * 32];
    short* sB0 = &lB[(wave * 32) * 32];
    short* sB1 = &lB[(wave * 32 + 16) * 32];

    for (int k0 = 0; k0 < DIN; k0 += 32) {
        gload_lds16(gA0 + k0, sA0);
        gload_lds16(gA1 + k0, sA1);
        gload_lds16(gB0 + k0, sB0);
        gload_lds16(gB1 + k0, sB1);
        __syncthreads();
        bf16x8 af[4], bs[2], bff[2];
        #pragma unroll
        for (int t = 0; t < 4; ++t)
            af[t]  = *(const bf16x8*)&lA[(wm * 64 + t * 16 + l16) * 32 + quad * 8];
        #pragma unroll
        for (int t = 0; t < 2; ++t) {
            bs[t]  = *(const bf16x8*)&lB[(wn * 32 + t * 16 + l16) * 32 + quad * 8];
            bff[t] = *(const bf16x8*)&lB[(64 + wn * 32 + t * 16 + l16) * 32 + quad * 8];
        }
        #pragma unroll
        for (int tm = 0; tm < 4; ++tm)
            #pragma unroll
            for (int tn = 0; tn < 2; ++tn) {
                accS[tm][tn] = __builtin_amdgcn_mfma_f32_16x16x32_bf16(af[tm], bs[tn],  accS[tm][tn], 0, 0, 0);
                accF[tm][tn] = __builtin_amdgcn_mfma_f32_16x16x32_bf16(af[tm], bff[tn], accF[tm][tn], 0, 0, 0);
            }
        __syncthreads();
    }

    const float a = alpha[0];
    float cp0 = 0.f, cp1 = 0.f;
    #pragma unroll
    for (int tm = 0; tm < 4; ++tm) {
        const int r0 = m0 + wm * 64 + tm * 16 + quad * 4;
        #pragma unroll
        for (int tn = 0; tn < 2; ++tn) {
            const int cc = n0 + wn * 32 + tn * 16 + l16;
            short4 s4;
            #pragma unroll
            for (int r = 0; r < 4; ++r) {
                const float fs = accS[tm][tn][r];
                const float ff = accF[tm][tn][r];
                slow_out[(size_t)(r0 + r) * 1024 + cc] = fs;
                comb_out[(size_t)(r0 + r) * 1024 + cc] = fs + a * ff;
                if (tn == 0) cp0 += ff * ff; else cp1 += ff * ff;
                ((short*)&s4)[r] = f2bf(ff);
            }
            // fastT[cc][r0..r0+3] — contiguous along m, 8B aligned (r0 % 4 == 0)
            *(short4*)&fastT[(size_t)cc * B_SZ + r0] = s4;
        }
    }
    // reduce cp over the 4 quads (lanes differing in bits 4,5), then one atomic per col
    cp0 += __shfl_xor(cp0, 16); cp0 += __shfl_xor(cp0, 32);
    cp1 += __shfl_xor(cp1, 16); cp1 += __shfl_xor(cp1, 32);
    if (quad == 0) {
        atomicAdd(&csq[n0 + wn * 32 + l16], cp0);
        atomicAdd(&csq[n0 + wn * 32 + 16 + l16], cp1);
    }
}

// ---------------- hebb GEMM (m97 structure, split-K): hebb = fastT @ xT^T ----------------
__global__ __launch_bounds__(256) void hebb_gemm(
    const short* __restrict__ fastT,  // [DOUT, B]
    const short* __restrict__ xT,     // [DIN, B]
    short* __restrict__ hebb_part)    // [SPLITK][DOUT, DIN] bf16
{
    __shared__ short lA[128 * 32];
    __shared__ short lB[128 * 32];
    const int tid = threadIdx.x;
    const int lane = tid & 63;
    const int wave = tid >> 6;
    const int wm = wave & 1, wn = wave >> 1;
    const int quad = lane >> 4, l16 = lane & 15;
    const int m0 = blockIdx.x * 128;   // dout
    const int n0 = blockIdx.y * 128;   // din
    const int kb = blockIdx.z * (B_SZ / SPLITK);
    const int lrow = lane >> 2;
    const int lcol = (lane & 3) * 8;

    f32x4 acc[4][4] = {};

    const short* gA0 = &fastT[(size_t)(m0 + wave * 32 + lrow) * B_SZ + kb + lcol];
    const short* gA1 = gA0 + (size_t)16 * B_SZ;
    const short* gB0 = &xT[(size_t)(n0 + wave * 32 + lrow) * B_SZ + kb + lcol];
    const short* gB1 = gB0 + (size_t)16 * B_SZ;
    short* sA0 = &lA[(wave * 32) * 32];
    short* sA1 = &lA[(wave * 32 + 16) * 32];
    short* sB0 = &lB[(wave * 32) * 32];
    short* sB1 = &lB[(wave * 32 + 16) * 32];

    for (int k0 = 0; k0 < B_SZ / SPLITK; k0 += 32) {
        gload_lds16(gA0 + k0, sA0);
        gload_lds16(gA1 + k0, sA1);
        gload_lds16(gB0 + k0, sB0);
        gload_lds16(gB1 + k0, sB1);
        __syncthreads();
        bf16x8 af[4], bfr[4];
        #pragma unroll
        for (int t = 0; t < 4; ++t) {
            af[t]  = *(const bf16x8*)&lA[(wm * 64 + t * 16 + l16) * 32 + quad * 8];
            bfr[t] = *(const bf16x8*)&lB[(wn * 64 + t * 16 + l16) * 32 + quad * 8];
        }
        #pragma unroll
        for (int tm = 0; tm < 4; ++tm)
            #pragma unroll
            for (int tn = 0; tn < 4; ++tn)
                acc[tm][tn] = __builtin_amdgcn_mfma_f32_16x16x32_bf16(af[tm], bfr[tn], acc[tm][tn], 0, 0, 0);
        __syncthreads();
    }
    short* dst = hebb_part + (size_t)blockIdx.z * DOUT * DIN;
    #pragma unroll
    for (int tm = 0; tm < 4; ++tm) {
        int r0 = m0 + wm * 64 + tm * 16 + quad * 4;
        #pragma unroll
        for (int tn = 0; tn < 4; ++tn) {
            int cc = n0 + wn * 64 + tn * 16 + l16;
            #pragma unroll
            for (int r = 0; r < 4; ++r)
                dst[(size_t)(r0 + r) * DIN + cc] = f2bf(acc[tm][tn][r]);
        }
    }
}

// ---------------- LEGACY: colsumsq from fastT (deterministic, no atomics) ----------------
__global__ __launch_bounds__(256) void colsumsq_kernel(const short* __restrict__ fastT,
                                                       float* __restrict__ sums) {
    const int m = blockIdx.x;
    const int tid = threadIdx.x;
    const short* row = &fastT[(size_t)m * B_SZ];
    float s = 0.f;
    for (int i = tid * 8; i < B_SZ; i += 256 * 8) {
        bf16x8 v = *(const bf16x8*)&row[i];
        #pragma unroll
        for (int j = 0; j < 8; ++j) { float f = bf2f(v[j]); s += f * f; }
    }
    __shared__ float red[256];
    red[tid] = s; __syncthreads();
    for (int off = 128; off > 0; off >>= 1) {
        if (tid < off) red[tid] += red[tid + off];
        __syncthreads();
    }
    if (tid == 0) sums[m] = red[0];
}

// ---------------- W_fast update with tanh epilogue ----------------
__global__ __launch_bounds__(256) void wfast_update(
    const float* __restrict__ Wf, const short* __restrict__ hebb_part,
    const float* __restrict__ colsumsq, const float* __restrict__ eff_lr,
    float* __restrict__ Wf_new)
{
    const int i0 = (blockIdx.x * 256 + threadIdx.x) * 8;
    const int m = i0 >> 10;
    const float lr = eff_lr[0];
    const float fgm = colsumsq[m] * (1.0f / (float)B_SZ);
    float h[8] = {0.f, 0.f, 0.f, 0.f, 0.f, 0.f, 0.f, 0.f};
    #pragma unroll
    for (int z = 0; z < SPLITK; ++z) {
        bf16x8 v = *(const bf16x8*)&hebb_part[(size_t)z * DOUT * DIN + i0];
        #pragma unroll
        for (int j = 0; j < 8; ++j) h[j] += bf2f(v[j]);
    }
    float4 w0 = *(const float4*)&Wf[i0];
    float4 w1 = *(const float4*)&Wf[i0 + 4];
    float w[8] = {w0.x, w0.y, w0.z, w0.w, w1.x, w1.y, w1.z, w1.w};
    float o[8];
    #pragma unroll
    for (int j = 0; j < 8; ++j)
        o[j] = w[j] + tanhf(h[j] * (1.0f / (float)B_SZ) - fgm * w[j]) * lr;
    *(float4*)&Wf_new[i0]     = make_float4(o[0], o[1], o[2], o[3]);
    *(float4*)&Wf_new[i0 + 4] = make_float4(o[4], o[5], o[6], o[7]);
}

// ---------------- LEGACY combine + LayerNorm (in-place over fast) ----------------
__global__ __launch_bounds__(256) void ln_kernel(
    const float* __restrict__ slow, float* __restrict__ io,
    const float* __restrict__ gamma, const float* __restrict__ beta,
    const float* __restrict__ alpha)
{
    const int row = blockIdx.x;
    const int tid = threadIdx.x;
    const float a = alpha[0];
    const size_t base = (size_t)row * DOUT;
    float c[4];
    float s = 0.f, ss = 0.f;
    #pragma unroll
    for (int i = 0; i < 4; ++i) {
        int col = tid + i * 256;
        float v = slow[base + col] + a * io[base + col];
        c[i] = v; s += v; ss += v * v;
    }
    #pragma unroll
    for (int off = 32; off > 0; off >>= 1) {
        s  += __shfl_down(s, off);
        ss += __shfl_down(ss, off);
    }
    __shared__ float rs[4], rss[4];
    int wave = tid >> 6;
    if ((tid & 63) == 0) { rs[wave] = s; rss[wave] = ss; }
    __syncthreads();
    float S  = rs[0] + rs[1] + rs[2] + rs[3];
    float SS = rss[0] + rss[1] + rss[2] + rss[3];
    float mu = S * (1.0f / DOUT);
    float var = SS * (1.0f / DOUT) - mu * mu;
    float inv = rsqrtf(var + 1e-5f);
    #pragma unroll
    for (int i = 0; i < 4; ++i) {
        int col = tid + i * 256;
        io[base + col] = (c[i] - mu) * inv * gamma[col] + beta[col];
    }
}

// ---------------- FUSED LayerNorm (combined precomputed, in-place) ----------------
__global__ __launch_bounds__(256) void ln_fused(
    float* __restrict__ io,
    const float* __restrict__ gamma, const float* __restrict__ beta)
{
    const int row = blockIdx.x;
    const int tid = threadIdx.x;
    const size_t base = (size_t)row * DOUT;
    float c[4];
    float s = 0.f, ss = 0.f;
    #pragma unroll
    for (int i = 0; i < 4; ++i) {
        int col = tid + i * 256;
        float v = io[base + col];
        c[i] = v; s += v; ss += v * v;
    }
    #pragma unroll
    for (int off = 32; off > 0; off >>= 1) {
        s  += __shfl_down(s, off);
        ss += __shfl_down(ss, off);
    }
    __shared__ float rs[4], rss[4];
    int wave = tid >> 6;
    if ((tid & 63) == 0) { rs[wave] = s; rss[wave] = ss; }
    __syncthreads();
    float S  = rs[0] + rs[1] + rs[2] + rs[3];
    float SS = rss[0] + rss[1] + rss[2] + rss[3];
    float mu = S * (1.0f / DOUT);
    float var = SS * (1.0f / DOUT) - mu * mu;
    float inv = rsqrtf(var + 1e-5f);
    #pragma unroll
    for (int i = 0; i < 4; ++i) {
        int col = tid + i * 256;
        io[base + col] = (c[i] - mu) * inv * gamma[col] + beta[col];
    }
}

extern "C" void kernel_launch(void* const* d_in, const int* in_sizes, int n_in,
                              void* d_out, int out_size, void* d_ws, size_t ws_size,
                              hipStream_t stream)
{
    const float* x     = (const float*)d_in[0];
    const float* plast = (const float*)d_in[1];
    const float* alpha = (const float*)d_in[2];
    const float* Wslow = (const float*)d_in[3];
    const float* Wfast = (const float*)d_in[4];
    const float* gamma = (const float*)d_in[5];
    const float* beta  = (const float*)d_in[6];

    float* out   = (float*)d_out;                 // [B, DOUT]; holds combined until LN (fused) / fast (legacy)
    float* slow  = out + (size_t)B_SZ * DOUT;     // [B, DOUT]
    float* wfnew = slow + (size_t)B_SZ * DOUT;    // [DOUT, DIN]

    char* ws = (char*)d_ws;
    const size_t SZ_XB   = (size_t)B_SZ * DIN * 2;          // 32 MB
    const size_t SZ_XT   = (size_t)DIN * B_SZ * 2;          // 32 MB
    const size_t SZ_WCAT = (size_t)2048 * DIN * 2;          // 4 MB
    const size_t SZ_HEBB = (size_t)SPLITK * DOUT * DIN * 2; // 16 MB
    const size_t SZ_FT   = (size_t)DOUT * B_SZ * 2;         // 32 MB

    // fused layout: xb | xT | wcat | hebb | fastT | csq | efflr
    const size_t need_fused = SZ_XB + SZ_XT + SZ_WCAT + SZ_HEBB + SZ_FT + 4096 + 256;
    const bool fused = (ws_size >= need_fused);

    if (fused) {
        short* xb    = (short*)ws;
        short* xT    = (short*)(ws + SZ_XB);
        short* wcat  = (short*)(ws + SZ_XB + SZ_XT);
        short* hebb  = (short*)(ws + SZ_XB + SZ_XT + SZ_WCAT);
        short* fastT = (short*)(ws + SZ_XB + SZ_XT + SZ_WCAT + SZ_HEBB);
        float* csq   = (float*)(ws + SZ_XB + SZ_XT + SZ_WCAT + SZ_HEBB + SZ_FT);
        float* efflr = csq + DOUT;

        x_convert<<<dim3(B_SZ / 64, DIN / 64), 256, 0, stream>>>(x, xb, xT);
        convert_f32_bf16<<<(DOUT * DIN / 4 + 255) / 256, 256, 0, stream>>>(Wslow, wcat, DOUT * DIN / 4);
        convert_f32_bf16<<<(DOUT * DIN / 4 + 255) / 256, 256, 0, stream>>>(Wfast, wcat + (size_t)DOUT * DIN, DOUT * DIN / 4);
        init_kernel<<<1, 256, 0, stream>>>(plast, efflr, csq);
        dual_gemm_fused<<<dim3(B_SZ / 128, 1024 / 64), 256, 0, stream>>>(
            xb, wcat, slow, out, fastT, csq, alpha);
        hebb_gemm<<<dim3(DOUT / 128, DIN / 128, SPLITK), 256, 0, stream>>>(fastT, xT, hebb);
        wfast_update<<<(DOUT * DIN) / (256 * 8), 256, 0, stream>>>(Wfast, hebb, csq, efflr, wfnew);
        ln_fused<<<B_SZ, 256, 0, stream>>>(out, gamma, beta);
    } else {
        // legacy pipeline (fastT aliases xb; xb dead after dual_gemm)
        short* xb    = (short*)ws;
        short* fastT = xb;
        short* xT    = (short*)(ws + SZ_XB);
        short* wcat  = (short*)(ws + SZ_XB + SZ_XT);
        short* hebb  = (short*)(ws + SZ_XB + SZ_XT + SZ_WCAT);
        float* csq   = (float*)(ws + SZ_XB + SZ_XT + SZ_WCAT + SZ_HEBB);
        float* efflr = csq + DOUT;

        x_convert<<<dim3(B_SZ / 64, DIN / 64), 256, 0, stream>>>(x, xb, xT);
        convert_f32_bf16<<<(DOUT * DIN / 4 + 255) / 256, 256, 0, stream>>>(Wslow, wcat, DOUT * DIN / 4);
        convert_f32_bf16<<<(DOUT * DIN / 4 + 255) / 256, 256, 0, stream>>>(Wfast, wcat + (size_t)DOUT * DIN, DOUT * DIN / 4);
        init_kernel<<<1, 256, 0, stream>>>(plast, efflr, csq);
        dual_gemm<<<dim3(B_SZ / 128, 2048 / 128), 256, 0, stream>>>(xb, wcat, slow, out);
        fast_trans<<<dim3(B_SZ / 64, DOUT / 64), 256, 0, stream>>>(out, fastT);
        colsumsq_kernel<<<DOUT, 256, 0, stream>>>(fastT, csq);
        hebb_gemm<<<dim3(DOUT / 128, DIN / 128, SPLITK), 256, 0, stream>>>(fastT, xT, hebb);
        wfast_update<<<(DOUT * DIN) / (256 * 8), 256, 0, stream>>>(Wfast, hebb, csq, efflr, wfnew);
        ln_kernel<<<B_SZ, 256, 0, stream>>>(slow, out, gamma, beta, alpha);
    }
}

// Round 3
// 405.129 us; speedup vs baseline: 1.1151x; 1.1151x over previous
//
#include <hip/hip_runtime.h>
#include <cstdint>
#include <cstddef>

#define B_SZ 16384
#define DIN  1024
#define DOUT 1024
#define SPLITK 16

typedef short bf16x8 __attribute__((ext_vector_type(8)));
typedef float f32x4  __attribute__((ext_vector_type(4)));

static __device__ __forceinline__ short f2bf(float f) {
    union { float f; unsigned u; } v; v.f = f;
    unsigned r = v.u + 0x7fffu + ((v.u >> 16) & 1u);
    return (short)(r >> 16);
}
static __device__ __forceinline__ float bf2f(short s) {
    union { unsigned u; float f; } v; v.u = ((unsigned)(unsigned short)s) << 16;
    return v.f;
}
// async global->LDS, 16B per lane; LDS dest is wave-uniform base + lane*16 (linear)
static __device__ __forceinline__ void gload_lds16(const short* g, short* l) {
    __builtin_amdgcn_global_load_lds(
        (const __attribute__((address_space(1))) void*)g,
        (__attribute__((address_space(3))) void*)l, 16, 0, 0);
}

// ---------------- fp32 -> bf16 convert (for weights) ----------------
__global__ __launch_bounds__(256) void convert_f32_bf16(const float* __restrict__ in,
                                                        short* __restrict__ out, int n4) {
    int i = blockIdx.x * 256 + threadIdx.x;
    if (i < n4) {
        float4 v = ((const float4*)in)[i];
        short4 o;
        o.x = f2bf(v.x); o.y = f2bf(v.y); o.z = f2bf(v.z); o.w = f2bf(v.w);
        ((short4*)out)[i] = o;
    }
}

// ---------------- x: fp32 [B,DIN] -> xb bf16 [B,DIN] + xT bf16 [DIN,B] ----------------
__global__ __launch_bounds__(256) void x_convert(const float* __restrict__ x,
                                                 short* __restrict__ xb,
                                                 short* __restrict__ xT) {
    __shared__ short t[64 * 72];
    const int b0 = blockIdx.x * 64;
    const int d0 = blockIdx.y * 64;
    const int tid = threadIdx.x;
    const int r = tid >> 2;            // batch row 0..63
    const int c = (tid & 3) * 16;      // col seg
    short loc[16];
    #pragma unroll
    for (int i = 0; i < 4; ++i) {
        float4 v = *(const float4*)&x[(size_t)(b0 + r) * DIN + d0 + c + i * 4];
        loc[i * 4 + 0] = f2bf(v.x); loc[i * 4 + 1] = f2bf(v.y);
        loc[i * 4 + 2] = f2bf(v.z); loc[i * 4 + 3] = f2bf(v.w);
    }
    *(bf16x8*)&xb[(size_t)(b0 + r) * DIN + d0 + c]     = *(bf16x8*)&loc[0];
    *(bf16x8*)&xb[(size_t)(b0 + r) * DIN + d0 + c + 8] = *(bf16x8*)&loc[8];
    #pragma unroll
    for (int i = 0; i < 16; ++i) t[(c + i) * 72 + r] = loc[i];
    __syncthreads();
    const int d = tid >> 2, bs = (tid & 3) * 16;
    *(bf16x8*)&xT[(size_t)(d0 + d) * B_SZ + b0 + bs]     = *(bf16x8*)&t[d * 72 + bs];
    *(bf16x8*)&xT[(size_t)(d0 + d) * B_SZ + b0 + bs + 8] = *(bf16x8*)&t[d * 72 + bs + 8];
}

// ---------------- fast fp32 [B,DOUT] -> fastT bf16 [DOUT,B] ----------------
__global__ __launch_bounds__(256) void fast_trans(const float* __restrict__ fast,
                                                  short* __restrict__ fastT) {
    __shared__ short t[64 * 72];
    const int b0 = blockIdx.x * 64;
    const int d0 = blockIdx.y * 64;
    const int tid = threadIdx.x;
    const int r = tid >> 2;
    const int c = (tid & 3) * 16;
    short loc[16];
    #pragma unroll
    for (int i = 0; i < 4; ++i) {
        float4 v = *(const float4*)&fast[(size_t)(b0 + r) * DOUT + d0 + c + i * 4];
        loc[i * 4 + 0] = f2bf(v.x); loc[i * 4 + 1] = f2bf(v.y);
        loc[i * 4 + 2] = f2bf(v.z); loc[i * 4 + 3] = f2bf(v.w);
    }
    #pragma unroll
    for (int i = 0; i < 16; ++i) t[(c + i) * 72 + r] = loc[i];
    __syncthreads();
    const int d = tid >> 2, bs = (tid & 3) * 16;
    *(bf16x8*)&fastT[(size_t)(d0 + d) * B_SZ + b0 + bs]     = *(bf16x8*)&t[d * 72 + bs];
    *(bf16x8*)&fastT[(size_t)(d0 + d) * B_SZ + b0 + bs + 8] = *(bf16x8*)&t[d * 72 + bs + 8];
}

// ---------------- init: eff_lr + zero csq ----------------
__global__ __launch_bounds__(256) void init_kernel(const float* __restrict__ plast,
                                                   float* __restrict__ eff_lr,
                                                   float* __restrict__ csq) {
    int tid = threadIdx.x;
    for (int i = tid; i < DOUT; i += 256) csq[i] = 0.f;
    float s = 0.f;
    for (int i = tid; i < B_SZ; i += 256) s += plast[i];
    __shared__ float red[256];
    red[tid] = s; __syncthreads();
    for (int off = 128; off > 0; off >>= 1) {
        if (tid < off) red[tid] += red[tid + off];
        __syncthreads();
    }
    if (tid == 0) eff_lr[0] = (red[0] / (float)B_SZ) * 0.1f;
}

// ================= 256x256 8-phase GEMM core (m201 template, plain HIP) =================
// C = A @ B^T. A row-major [M,K] (ld=lda), B row-major [N,K] (ld=ldb). K per call = 1024
// (NT=16 K-tiles of 64, 7 iterations of 2 tiles + drained last iteration). 8 waves
// (2M x 4N), 128 KiB LDS, st_16x32 swizzle via pre-swizzled global source (linear
// gload_lds dest) + same XOR on ds_read. vmcnt(4) only at phases 4/8 in main loop.
#define PRIO1 __builtin_amdgcn_s_setprio(1)
#define PRIO0 __builtin_amdgcn_s_setprio(0)
#define BARX  asm volatile("s_barrier" ::: "memory")
#define LGKM0 asm volatile("s_waitcnt lgkmcnt(0)" ::: "memory")
#define VMC4  asm volatile("s_waitcnt vmcnt(4)" ::: "memory")
#define VMC0  asm volatile("s_waitcnt vmcnt(0)" ::: "memory")

// stage one half-tile (128 rows x 64 cols bf16 = 2 x gload_lds16 issues)
#define STG(RO, SRC, LD, KT, H) do { \
    const short* _s = (SRC) + (size_t)((H) * 128 + srow) * (LD) + (KT) * 64 + scol; \
    gload_lds16(_s, &L[(RO) + ((H) * 128 + wrow8) * 64]); \
    gload_lds16(_s + (size_t)64 * (LD), &L[(RO) + ((H) * 128 + 64 + wrow8) * 64]); \
} while (0)

// read A m-half: 8 x ds_read_b128
#define RDA(RO, MH) do { \
    const int _rb = (RO) + (wm * 128 + (MH) * 64 + l16) * 64 + qx; \
    _Pragma("unroll") for (int mf = 0; mf < 4; ++mf) { \
        a_[mf][0] = *(const bf16x8*)&L[_rb + mf * 1024]; \
        a_[mf][1] = *(const bf16x8*)&L[_rb + mf * 1024 + 32]; \
    } \
} while (0)

// read B n-half: 4 x ds_read_b128 (kept resident: b_[0] and b_[1])
#define RDB(RO, NH) do { \
    const int _rb = (RO) + (wn * 64 + (NH) * 32 + l16) * 64 + qx; \
    _Pragma("unroll") for (int nf = 0; nf < 2; ++nf) { \
        b_[NH][nf][0] = *(const bf16x8*)&L[_rb + nf * 1024]; \
        b_[NH][nf][1] = *(const bf16x8*)&L[_rb + nf * 1024 + 32]; \
    } \
} while (0)

// 16 MFMA: one C-quadrant x K=64
#define MM(MH, NH) do { \
    _Pragma("unroll") for (int mf = 0; mf < 4; ++mf) \
    _Pragma("unroll") for (int nf = 0; nf < 2; ++nf) { \
        acc[(MH)*4+mf][(NH)*2+nf] = __builtin_amdgcn_mfma_f32_16x16x32_bf16(a_[mf][0], b_[NH][nf][0], acc[(MH)*4+mf][(NH)*2+nf], 0, 0, 0); \
        acc[(MH)*4+mf][(NH)*2+nf] = __builtin_amdgcn_mfma_f32_16x16x32_bf16(a_[mf][1], b_[NH][nf][1], acc[(MH)*4+mf][(NH)*2+nf], 0, 0, 0); \
    } \
} while (0)

template<int EPI>
static __device__ __forceinline__ void gemm256_core(
    const short* __restrict__ Asrc, int lda,   // at [m0, k0]
    const short* __restrict__ Bsrc, int ldb,   // at [n0, k0]
    float* __restrict__ dstf,                  // EPI=0: fp32 out base [*,1024]
    short* __restrict__ dsth,                  // EPI=1: bf16 out base [*,DIN]
    int m0, int cb)
{
    __shared__ short L[65536];   // 128 KB: A0 | A1 | B0 | B1, each 256x64 bf16
    const int A0o = 0, A1o = 16384, B0o = 32768, B1o = 49152;
    const int tid  = threadIdx.x;
    const int lane = tid & 63;
    const int w    = tid >> 6;           // 0..7
    const int wm   = w >> 2;             // 0..1
    const int wn   = w & 3;              // 0..3
    const int quad = lane >> 4;
    const int l16  = lane & 15;
    const int qx   = (quad * 8) ^ ((lane & 4) ? 16 : 0);   // swizzled k-col (shorts)
    const int wrow8 = w * 8;
    const int srow  = tid >> 3;                             // staging row 0..63
    const int scol  = ((lane & 7) * 8) ^ ((lane & 32) >> 1);// pre-swizzled src col

    f32x4 acc[8][4] = {};
    bf16x8 a_[4][2];
    bf16x8 b_[2][2][2];

    // prologue: tile0 -> buf0 (B,A), tile1 B -> buf1; wait all but last 4, barrier
    STG(B0o, Bsrc, ldb, 0, 0); STG(B0o, Bsrc, ldb, 0, 1);
    STG(A0o, Asrc, lda, 0, 0); STG(A0o, Asrc, lda, 0, 1);
    STG(B1o, Bsrc, ldb, 1, 0); STG(B1o, Bsrc, ldb, 1, 1);
    VMC4; BARX;

    for (int it = 0; it < 7; ++it) {
        const int t = 2 * it;
        // ---- group 1: compute buf0 (tile t) ----
        RDA(A0o, 0); RDB(B0o, 0); STG(A1o, Asrc, lda, t + 1, 0);
        BARX; LGKM0; PRIO1; MM(0, 0); PRIO0; BARX;
        RDB(B0o, 1); STG(A1o, Asrc, lda, t + 1, 1);
        BARX; LGKM0; PRIO1; MM(0, 1); PRIO0; BARX;
        RDA(A0o, 1); STG(B0o, Bsrc, ldb, t + 2, 0);
        BARX; LGKM0; PRIO1; MM(1, 1); PRIO0; BARX;
        STG(B0o, Bsrc, ldb, t + 2, 1);
        BARX; PRIO1; MM(1, 0); PRIO0; VMC4; BARX;
        // ---- group 2: compute buf1 (tile t+1) ----
        RDA(A1o, 0); RDB(B1o, 0); STG(A0o, Asrc, lda, t + 2, 0);
        BARX; LGKM0; PRIO1; MM(0, 0); PRIO0; BARX;
        RDB(B1o, 1); STG(A0o, Asrc, lda, t + 2, 1);
        BARX; LGKM0; PRIO1; MM(0, 1); PRIO0; BARX;
        RDA(A1o, 1); STG(B1o, Bsrc, ldb, t + 3, 0);
        BARX; LGKM0; PRIO1; MM(1, 1); PRIO0; BARX;
        STG(B1o, Bsrc, ldb, t + 3, 1);
        BARX; PRIO1; MM(1, 0); PRIO0; VMC4; BARX;
    }
    // ---- last iteration (tiles 14,15) ----
    // FIX (R2 bug): A1 still holds tile 13 here — the ring stages A1<-t+1 just-in-time
    // in group 1. Stage A1<-15 during group 1, then VMC0 drains it (+B1<-15 already
    // in flight from it=6 phases 7-8) before group 2 reads buf1.
    RDA(A0o, 0); RDB(B0o, 0); STG(A1o, Asrc, lda, 15, 0);
    BARX; LGKM0; PRIO1; MM(0, 0); PRIO0; BARX;
    RDB(B0o, 1); STG(A1o, Asrc, lda, 15, 1);
    BARX; LGKM0; PRIO1; MM(0, 1); PRIO0; BARX;
    RDA(A0o, 1);
    BARX; LGKM0; PRIO1; MM(1, 1); PRIO0; BARX;
    BARX; PRIO1; MM(1, 0); PRIO0; VMC0; BARX;
    RDA(A1o, 0); RDB(B1o, 0);
    BARX; LGKM0; PRIO1; MM(0, 0); PRIO0; BARX;
    RDB(B1o, 1);
    BARX; LGKM0; PRIO1; MM(0, 1); PRIO0; BARX;
    RDA(A1o, 1);
    BARX; LGKM0; PRIO1; MM(1, 1); PRIO0; BARX;
    PRIO1; MM(1, 0); PRIO0;

    // ---- epilogue ----
    if (EPI == 0) {
        #pragma unroll
        for (int mf = 0; mf < 8; ++mf) {
            const int r0 = m0 + wm * 128 + mf * 16 + quad * 4;
            #pragma unroll
            for (int nf = 0; nf < 4; ++nf) {
                const int cc = cb + wn * 64 + nf * 16 + l16;
                #pragma unroll
                for (int r = 0; r < 4; ++r)
                    dstf[(size_t)(r0 + r) * 1024 + cc] = acc[mf][nf][r];
            }
        }
    } else {
        #pragma unroll
        for (int mf = 0; mf < 8; ++mf) {
            const int r0 = m0 + wm * 128 + mf * 16 + quad * 4;
            #pragma unroll
            for (int nf = 0; nf < 4; ++nf) {
                const int cc = cb + wn * 64 + nf * 16 + l16;
                #pragma unroll
                for (int r = 0; r < 4; ++r)
                    dsth[(size_t)(r0 + r) * DIN + cc] = f2bf(acc[mf][nf][r]);
            }
        }
    }
}

// dual GEMM: [16384,2048] = xb @ wcat^T; grid 512 (64 m x 8 n), XCD-swizzled
__global__ __launch_bounds__(512) void dual_gemm8(
    const short* __restrict__ Xb, const short* __restrict__ Wc,
    float* __restrict__ slow_out, float* __restrict__ fast_out)
{
    const int bid = blockIdx.x;                    // 512 blocks, 512 % 8 == 0
    const int id  = (bid & 7) * 64 + (bid >> 3);   // bijective XCD swizzle
    const int bm  = id & 63, bn = id >> 6;         // XCD owns one W-panel column
    const int m0  = bm * 256, n0 = bn * 256;
    float* dst = (n0 < 1024) ? slow_out : fast_out;
    gemm256_core<0>(&Xb[(size_t)m0 * DIN], DIN, &Wc[(size_t)n0 * DIN], DIN,
                    dst, nullptr, m0, n0 & 1023);
}

// hebb GEMM: hebb_part[z] = fastT[:,zK:] @ xT[:,zK:]^T; grid 4x4x16 = 256 blocks (1/CU)
__global__ __launch_bounds__(512) void hebb_gemm8(
    const short* __restrict__ fastT, const short* __restrict__ xT,
    short* __restrict__ hebb_part)
{
    const int m0 = blockIdx.x * 256;
    const int n0 = blockIdx.y * 256;
    const size_t kb = (size_t)blockIdx.z * (B_SZ / SPLITK);
    gemm256_core<1>(&fastT[(size_t)m0 * B_SZ + kb], B_SZ,
                    &xT[(size_t)n0 * B_SZ + kb], B_SZ,
                    nullptr, hebb_part + (size_t)blockIdx.z * DOUT * DIN, m0, n0);
}

// ---------------- colsumsq from fastT (deterministic, no atomics) ----------------
__global__ __launch_bounds__(256) void colsumsq_kernel(const short* __restrict__ fastT,
                                                       float* __restrict__ sums) {
    const int m = blockIdx.x;
    const int tid = threadIdx.x;
    const short* row = &fastT[(size_t)m * B_SZ];
    float s = 0.f;
    for (int i = tid * 8; i < B_SZ; i += 256 * 8) {
        bf16x8 v = *(const bf16x8*)&row[i];
        #pragma unroll
        for (int j = 0; j < 8; ++j) { float f = bf2f(v[j]); s += f * f; }
    }
    __shared__ float red[256];
    red[tid] = s; __syncthreads();
    for (int off = 128; off > 0; off >>= 1) {
        if (tid < off) red[tid] += red[tid + off];
        __syncthreads();
    }
    if (tid == 0) sums[m] = red[0];
}

// ---------------- W_fast update with tanh epilogue ----------------
__global__ __launch_bounds__(256) void wfast_update(
    const float* __restrict__ Wf, const short* __restrict__ hebb_part,
    const float* __restrict__ colsumsq, const float* __restrict__ eff_lr,
    float* __restrict__ Wf_new)
{
    const int i0 = (blockIdx.x * 256 + threadIdx.x) * 8;
    const int m = i0 >> 10;
    const float lr = eff_lr[0];
    const float fgm = colsumsq[m] * (1.0f / (float)B_SZ);
    float h[8] = {0.f, 0.f, 0.f, 0.f, 0.f, 0.f, 0.f, 0.f};
    #pragma unroll
    for (int z = 0; z < SPLITK; ++z) {
        bf16x8 v = *(const bf16x8*)&hebb_part[(size_t)z * DOUT * DIN + i0];
        #pragma unroll
        for (int j = 0; j < 8; ++j) h[j] += bf2f(v[j]);
    }
    float4 w0 = *(const float4*)&Wf[i0];
    float4 w1 = *(const float4*)&Wf[i0 + 4];
    float w[8] = {w0.x, w0.y, w0.z, w0.w, w1.x, w1.y, w1.z, w1.w};
    float o[8];
    #pragma unroll
    for (int j = 0; j < 8; ++j)
        o[j] = w[j] + tanhf(h[j] * (1.0f / (float)B_SZ) - fgm * w[j]) * lr;
    *(float4*)&Wf_new[i0]     = make_float4(o[0], o[1], o[2], o[3]);
    *(float4*)&Wf_new[i0 + 4] = make_float4(o[4], o[5], o[6], o[7]);
}

// ---------------- combine + LayerNorm (in-place over fast) ----------------
__global__ __launch_bounds__(256) void ln_kernel(
    const float* __restrict__ slow, float* __restrict__ io,
    const float* __restrict__ gamma, const float* __restrict__ beta,
    const float* __restrict__ alpha)
{
    const int row = blockIdx.x;
    const int tid = threadIdx.x;
    const float a = alpha[0];
    const size_t base = (size_t)row * DOUT;
    float c[4];
    float s = 0.f, ss = 0.f;
    #pragma unroll
    for (int i = 0; i < 4; ++i) {
        int col = tid + i * 256;
        float v = slow[base + col] + a * io[base + col];
        c[i] = v; s += v; ss += v * v;
    }
    #pragma unroll
    for (int off = 32; off > 0; off >>= 1) {
        s  += __shfl_down(s, off);
        ss += __shfl_down(ss, off);
    }
    __shared__ float rs[4], rss[4];
    int wave = tid >> 6;
    if ((tid & 63) == 0) { rs[wave] = s; rss[wave] = ss; }
    __syncthreads();
    float S  = rs[0] + rs[1] + rs[2] + rs[3];
    float SS = rss[0] + rss[1] + rss[2] + rss[3];
    float mu = S * (1.0f / DOUT);
    float var = SS * (1.0f / DOUT) - mu * mu;
    float inv = rsqrtf(var + 1e-5f);
    #pragma unroll
    for (int i = 0; i < 4; ++i) {
        int col = tid + i * 256;
        io[base + col] = (c[i] - mu) * inv * gamma[col] + beta[col];
    }
}

extern "C" void kernel_launch(void* const* d_in, const int* in_sizes, int n_in,
                              void* d_out, int out_size, void* d_ws, size_t ws_size,
                              hipStream_t stream)
{
    const float* x     = (const float*)d_in[0];
    const float* plast = (const float*)d_in[1];
    const float* alpha = (const float*)d_in[2];
    const float* Wslow = (const float*)d_in[3];
    const float* Wfast = (const float*)d_in[4];
    const float* gamma = (const float*)d_in[5];
    const float* beta  = (const float*)d_in[6];

    float* out   = (float*)d_out;                 // [B, DOUT]; holds fast until LN
    float* slow  = out + (size_t)B_SZ * DOUT;     // [B, DOUT]
    float* wfnew = slow + (size_t)B_SZ * DOUT;    // [DOUT, DIN]

    // workspace layout (region A reused: xb until dual_gemm done, then fastT)
    char* ws = (char*)d_ws;
    const size_t SZ_XB   = (size_t)B_SZ * DIN * 2;           // 32 MB
    const size_t SZ_XT   = (size_t)DIN * B_SZ * 2;           // 32 MB
    const size_t SZ_WCAT = (size_t)2048 * DIN * 2;           // 4 MB
    const size_t SZ_HEBB = (size_t)SPLITK * DOUT * DIN * 2;  // 32 MB
    short* xb    = (short*)ws;
    short* fastT = xb;                                       // alias (xb dead after dual_gemm8)
    short* xT    = (short*)(ws + SZ_XB);
    short* wcat  = (short*)(ws + SZ_XB + SZ_XT);
    short* hebb  = (short*)(ws + SZ_XB + SZ_XT + SZ_WCAT);
    float* csq   = (float*)(ws + SZ_XB + SZ_XT + SZ_WCAT + SZ_HEBB);
    float* efflr = csq + DOUT;

    x_convert<<<dim3(B_SZ / 64, DIN / 64), 256, 0, stream>>>(x, xb, xT);
    convert_f32_bf16<<<(DOUT * DIN / 4 + 255) / 256, 256, 0, stream>>>(Wslow, wcat, DOUT * DIN / 4);
    convert_f32_bf16<<<(DOUT * DIN / 4 + 255) / 256, 256, 0, stream>>>(Wfast, wcat + (size_t)DOUT * DIN, DOUT * DIN / 4);
    init_kernel<<<1, 256, 0, stream>>>(plast, efflr, csq);
    dual_gemm8<<<512, 512, 0, stream>>>(xb, wcat, slow, out);
    fast_trans<<<dim3(B_SZ / 64, DOUT / 64), 256, 0, stream>>>(out, fastT);
    colsumsq_kernel<<<DOUT, 256, 0, stream>>>(fastT, csq);
    hebb_gemm8<<<dim3(DOUT / 256, DIN / 256, SPLITK), 512, 0, stream>>>(fastT, xT, hebb);
    wfast_update<<<(DOUT * DIN) / (256 * 8), 256, 0, stream>>>(Wfast, hebb, csq, efflr, wfnew);
    ln_kernel<<<B_SZ, 256, 0, stream>>>(slow, out, gamma, beta, alpha);
}

// Round 5
// 397.610 us; speedup vs baseline: 1.1362x; 1.0189x over previous
//
#include <hip/hip_runtime.h>
#include <cstdint>
#include <cstddef>

#define B_SZ 16384
#define DIN  1024
#define DOUT 1024
#define SPLITK 16

typedef short bf16x8 __attribute__((ext_vector_type(8)));
typedef float f32x4  __attribute__((ext_vector_type(4)));

static __device__ __forceinline__ short f2bf(float f) {
    union { float f; unsigned u; } v; v.f = f;
    unsigned r = v.u + 0x7fffu + ((v.u >> 16) & 1u);
    return (short)(r >> 16);
}
static __device__ __forceinline__ float bf2f(short s) {
    union { unsigned u; float f; } v; v.u = ((unsigned)(unsigned short)s) << 16;
    return v.f;
}
// async global->LDS, 16B per lane; LDS dest is wave-uniform base + lane*16 (linear)
static __device__ __forceinline__ void gload_lds16(const short* g, short* l) {
    __builtin_amdgcn_global_load_lds(
        (const __attribute__((address_space(1))) void*)g,
        (__attribute__((address_space(3))) void*)l, 16, 0, 0);
}

// ---------------- both weights fp32 -> bf16 into wcat [2048,1024] ----------------
__global__ __launch_bounds__(256) void convert_w2(const float* __restrict__ wsl,
                                                  const float* __restrict__ wfa,
                                                  short* __restrict__ out) {
    const int half = DOUT * DIN / 4;
    int i = blockIdx.x * 256 + threadIdx.x;
    const float* src = (i < half) ? wsl : wfa;
    int j = (i < half) ? i : i - half;
    float4 v = ((const float4*)src)[j];
    short4 o;
    o.x = f2bf(v.x); o.y = f2bf(v.y); o.z = f2bf(v.z); o.w = f2bf(v.w);
    ((short4*)out)[i] = o;
}

// ---------------- x: fp32 [B,DIN] -> xb bf16 [B,DIN] + xT bf16 [DIN,B] ----------------
__global__ __launch_bounds__(256) void x_convert(const float* __restrict__ x,
                                                 short* __restrict__ xb,
                                                 short* __restrict__ xT) {
    __shared__ short t[64 * 72];
    const int b0 = blockIdx.x * 64;
    const int d0 = blockIdx.y * 64;
    const int tid = threadIdx.x;
    const int r = tid >> 2;            // batch row 0..63
    const int c = (tid & 3) * 16;      // col seg
    short loc[16];
    #pragma unroll
    for (int i = 0; i < 4; ++i) {
        float4 v = *(const float4*)&x[(size_t)(b0 + r) * DIN + d0 + c + i * 4];
        loc[i * 4 + 0] = f2bf(v.x); loc[i * 4 + 1] = f2bf(v.y);
        loc[i * 4 + 2] = f2bf(v.z); loc[i * 4 + 3] = f2bf(v.w);
    }
    *(bf16x8*)&xb[(size_t)(b0 + r) * DIN + d0 + c]     = *(bf16x8*)&loc[0];
    *(bf16x8*)&xb[(size_t)(b0 + r) * DIN + d0 + c + 8] = *(bf16x8*)&loc[8];
    #pragma unroll
    for (int i = 0; i < 16; ++i) t[(c + i) * 72 + r] = loc[i];
    __syncthreads();
    const int d = tid >> 2, bs = (tid & 3) * 16;
    *(bf16x8*)&xT[(size_t)(d0 + d) * B_SZ + b0 + bs]     = *(bf16x8*)&t[d * 72 + bs];
    *(bf16x8*)&xT[(size_t)(d0 + d) * B_SZ + b0 + bs + 8] = *(bf16x8*)&t[d * 72 + bs + 8];
}

// ---------------- fast fp32 [B,DOUT] -> fastT bf16 [DOUT,B] ----------------
__global__ __launch_bounds__(256) void fast_trans(const float* __restrict__ fast,
                                                  short* __restrict__ fastT) {
    __shared__ short t[64 * 72];
    const int b0 = blockIdx.x * 64;
    const int d0 = blockIdx.y * 64;
    const int tid = threadIdx.x;
    const int r = tid >> 2;
    const int c = (tid & 3) * 16;
    short loc[16];
    #pragma unroll
    for (int i = 0; i < 4; ++i) {
        float4 v = *(const float4*)&fast[(size_t)(b0 + r) * DOUT + d0 + c + i * 4];
        loc[i * 4 + 0] = f2bf(v.x); loc[i * 4 + 1] = f2bf(v.y);
        loc[i * 4 + 2] = f2bf(v.z); loc[i * 4 + 3] = f2bf(v.w);
    }
    #pragma unroll
    for (int i = 0; i < 16; ++i) t[(c + i) * 72 + r] = loc[i];
    __syncthreads();
    const int d = tid >> 2, bs = (tid & 3) * 16;
    *(bf16x8*)&fastT[(size_t)(d0 + d) * B_SZ + b0 + bs]     = *(bf16x8*)&t[d * 72 + bs];
    *(bf16x8*)&fastT[(size_t)(d0 + d) * B_SZ + b0 + bs + 8] = *(bf16x8*)&t[d * 72 + bs + 8];
}

// ---------------- init: eff_lr + zero csq ----------------
__global__ __launch_bounds__(256) void init_kernel(const float* __restrict__ plast,
                                                   float* __restrict__ eff_lr,
                                                   float* __restrict__ csq) {
    int tid = threadIdx.x;
    for (int i = tid; i < DOUT; i += 256) csq[i] = 0.f;
    float s = 0.f;
    for (int i = tid; i < B_SZ; i += 256) s += plast[i];
    __shared__ float red[256];
    red[tid] = s; __syncthreads();
    for (int off = 128; off > 0; off >>= 1) {
        if (tid < off) red[tid] += red[tid + off];
        __syncthreads();
    }
    if (tid == 0) eff_lr[0] = (red[0] / (float)B_SZ) * 0.1f;
}

// ================= 256x256 8-phase GEMM core (m201 template, plain HIP) =================
// C = A @ B^T. A row-major [M,K] (ld=lda), B row-major [N,K] (ld=ldb). K per call = 1024
// (NT=16 K-tiles of 64). 8 waves (2M x 4N), 128 KiB LDS.
// LDS swizzle (G4 fix for 128B-row tiles): 16B-slot index XORed with (row&7), applied as
// the SAME involution on the staging global source (linear gload_lds dest) and the
// ds_read address. vmcnt(4) only at phases 4/8 in the main loop (never 0).
#define PRIO1 __builtin_amdgcn_s_setprio(1)
#define PRIO0 __builtin_amdgcn_s_setprio(0)
#define BARX  asm volatile("s_barrier" ::: "memory")
#define LGKM0 asm volatile("s_waitcnt lgkmcnt(0)" ::: "memory")
#define VMC4  asm volatile("s_waitcnt vmcnt(4)" ::: "memory")
#define VMC0  asm volatile("s_waitcnt vmcnt(0)" ::: "memory")

// stage one half-tile (128 rows x 64 cols bf16 = 2 x gload_lds16 issues)
// dest row&7 = lane>>3  ->  source 16B-slot pre-XORed by lane>>3
#define STG(RO, SRC, LD, KT, H) do { \
    const short* _s = (SRC) + (size_t)((H) * 128 + srow) * (LD) + (KT) * 64 + scol; \
    gload_lds16(_s, &L[(RO) + ((H) * 128 + wrow8) * 64]); \
    gload_lds16(_s + (size_t)64 * (LD), &L[(RO) + ((H) * 128 + 64 + wrow8) * 64]); \
} while (0)

// read A m-half: 8 x ds_read_b128; row&7 = l16&7 for all mf -> slot = (quad^4h)^(l16&7)
#define RDA(RO, MH) do { \
    const int _rb = (RO) + (wm * 128 + (MH) * 64 + l16) * 64; \
    _Pragma("unroll") for (int mf = 0; mf < 4; ++mf) { \
        a_[mf][0] = *(const bf16x8*)&L[_rb + mf * 1024 + c0]; \
        a_[mf][1] = *(const bf16x8*)&L[_rb + mf * 1024 + (c0 ^ 32)]; \
    } \
} while (0)

// read B n-half: 4 x ds_read_b128
#define RDB(RO, NH) do { \
    const int _rb = (RO) + (wn * 64 + (NH) * 32 + l16) * 64; \
    _Pragma("unroll") for (int nf = 0; nf < 2; ++nf) { \
        b_[NH][nf][0] = *(const bf16x8*)&L[_rb + nf * 1024 + c0]; \
        b_[NH][nf][1] = *(const bf16x8*)&L[_rb + nf * 1024 + (c0 ^ 32)]; \
    } \
} while (0)

// 16 MFMA: one C-quadrant x K=64
#define MM(MH, NH) do { \
    _Pragma("unroll") for (int mf = 0; mf < 4; ++mf) \
    _Pragma("unroll") for (int nf = 0; nf < 2; ++nf) { \
        acc[(MH)*4+mf][(NH)*2+nf] = __builtin_amdgcn_mfma_f32_16x16x32_bf16(a_[mf][0], b_[NH][nf][0], acc[(MH)*4+mf][(NH)*2+nf], 0, 0, 0); \
        acc[(MH)*4+mf][(NH)*2+nf] = __builtin_amdgcn_mfma_f32_16x16x32_bf16(a_[mf][1], b_[NH][nf][1], acc[(MH)*4+mf][(NH)*2+nf], 0, 0, 0); \
    } \
} while (0)

template<int EPI>
static __device__ __forceinline__ void gemm256_core(
    const short* __restrict__ Asrc, int lda,   // at [m0, k0]
    const short* __restrict__ Bsrc, int ldb,   // at [n0, k0]
    float* __restrict__ dstf,                  // EPI=0: fp32 out base [*,1024]
    short* __restrict__ dsth,                  // EPI=1: bf16 out base [*,DIN]
    int m0, int cb)
{
    __shared__ short L[65536];   // 128 KB: A0 | A1 | B0 | B1, each 256x64 bf16
    const int A0o = 0, A1o = 16384, B0o = 32768, B1o = 49152;
    const int tid  = threadIdx.x;
    const int lane = tid & 63;
    const int w    = tid >> 6;           // 0..7
    const int wm   = w >> 2;             // 0..1
    const int wn   = w & 3;              // 0..3
    const int quad = lane >> 4;
    const int l16  = lane & 15;
    const int c0   = ((quad ^ (l16 & 7)) << 3);             // swizzled 16B-slot (shorts)
    const int wrow8 = w * 8;
    const int srow  = tid >> 3;                             // staging row 0..63
    const int scol  = (((lane & 7) ^ (lane >> 3)) << 3);    // pre-swizzled src col

    f32x4 acc[8][4] = {};
    bf16x8 a_[4][2];
    bf16x8 b_[2][2][2];

    // prologue: tile0 -> buf0 (B,A), tile1 B -> buf1; wait all but last 4, barrier
    STG(B0o, Bsrc, ldb, 0, 0); STG(B0o, Bsrc, ldb, 0, 1);
    STG(A0o, Asrc, lda, 0, 0); STG(A0o, Asrc, lda, 0, 1);
    STG(B1o, Bsrc, ldb, 1, 0); STG(B1o, Bsrc, ldb, 1, 1);
    VMC4; BARX;

    for (int it = 0; it < 7; ++it) {
        const int t = 2 * it;
        // ---- group 1: compute buf0 (tile t) ----
        RDA(A0o, 0); RDB(B0o, 0); STG(A1o, Asrc, lda, t + 1, 0);
        BARX; LGKM0; PRIO1; MM(0, 0); PRIO0; BARX;
        RDB(B0o, 1); STG(A1o, Asrc, lda, t + 1, 1);
        BARX; LGKM0; PRIO1; MM(0, 1); PRIO0; BARX;
        RDA(A0o, 1); STG(B0o, Bsrc, ldb, t + 2, 0);
        BARX; LGKM0; PRIO1; MM(1, 1); PRIO0; BARX;
        STG(B0o, Bsrc, ldb, t + 2, 1);
        BARX; PRIO1; MM(1, 0); PRIO0; VMC4; BARX;
        // ---- group 2: compute buf1 (tile t+1) ----
        RDA(A1o, 0); RDB(B1o, 0); STG(A0o, Asrc, lda, t + 2, 0);
        BARX; LGKM0; PRIO1; MM(0, 0); PRIO0; BARX;
        RDB(B1o, 1); STG(A0o, Asrc, lda, t + 2, 1);
        BARX; LGKM0; PRIO1; MM(0, 1); PRIO0; BARX;
        RDA(A1o, 1); STG(B1o, Bsrc, ldb, t + 3, 0);
        BARX; LGKM0; PRIO1; MM(1, 1); PRIO0; BARX;
        STG(B1o, Bsrc, ldb, t + 3, 1);
        BARX; PRIO1; MM(1, 0); PRIO0; VMC4; BARX;
    }
    // ---- last iteration (tiles 14,15) ----
    // A1<-15 staged here (ring stages A1 just-in-time); VMC0 drains it + in-flight
    // B1<-15 before group 2 reads buf1.
    RDA(A0o, 0); RDB(B0o, 0); STG(A1o, Asrc, lda, 15, 0);
    BARX; LGKM0; PRIO1; MM(0, 0); PRIO0; BARX;
    RDB(B0o, 1); STG(A1o, Asrc, lda, 15, 1);
    BARX; LGKM0; PRIO1; MM(0, 1); PRIO0; BARX;
    RDA(A0o, 1);
    BARX; LGKM0; PRIO1; MM(1, 1); PRIO0; BARX;
    BARX; PRIO1; MM(1, 0); PRIO0; VMC0; BARX;
    RDA(A1o, 0); RDB(B1o, 0);
    BARX; LGKM0; PRIO1; MM(0, 0); PRIO0; BARX;
    RDB(B1o, 1);
    BARX; LGKM0; PRIO1; MM(0, 1); PRIO0; BARX;
    RDA(A1o, 1);
    BARX; LGKM0; PRIO1; MM(1, 1); PRIO0; BARX;
    PRIO1; MM(1, 0); PRIO0;

    // ---- epilogue ----
    if (EPI == 0) {
        #pragma unroll
        for (int mf = 0; mf < 8; ++mf) {
            const int r0 = m0 + wm * 128 + mf * 16 + quad * 4;
            #pragma unroll
            for (int nf = 0; nf < 4; ++nf) {
                const int cc = cb + wn * 64 + nf * 16 + l16;
                #pragma unroll
                for (int r = 0; r < 4; ++r)
                    dstf[(size_t)(r0 + r) * 1024 + cc] = acc[mf][nf][r];
            }
        }
    } else {
        #pragma unroll
        for (int mf = 0; mf < 8; ++mf) {
            const int r0 = m0 + wm * 128 + mf * 16 + quad * 4;
            #pragma unroll
            for (int nf = 0; nf < 4; ++nf) {
                const int cc = cb + wn * 64 + nf * 16 + l16;
                #pragma unroll
                for (int r = 0; r < 4; ++r)
                    dsth[(size_t)(r0 + r) * DIN + cc] = f2bf(acc[mf][nf][r]);
            }
        }
    }
}

// dual GEMM: [16384,2048] = xb @ wcat^T; grid 512 (64 m x 8 n), XCD-swizzled
__global__ __launch_bounds__(512) void dual_gemm8(
    const short* __restrict__ Xb, const short* __restrict__ Wc,
    float* __restrict__ slow_out, float* __restrict__ fast_out)
{
    const int bid = blockIdx.x;                    // 512 blocks, 512 % 8 == 0
    const int id  = (bid & 7) * 64 + (bid >> 3);   // bijective XCD swizzle
    const int bm  = id & 63, bn = id >> 6;         // XCD owns one W-panel column
    const int m0  = bm * 256, n0 = bn * 256;
    float* dst = (n0 < 1024) ? slow_out : fast_out;
    gemm256_core<0>(&Xb[(size_t)m0 * DIN], DIN, &Wc[(size_t)n0 * DIN], DIN,
                    dst, nullptr, m0, n0 & 1023);
}

// hebb GEMM: hebb_part[z] = fastT[:,zK:] @ xT[:,zK:]^T; grid 4x4x16 = 256 blocks (1/CU)
__global__ __launch_bounds__(512) void hebb_gemm8(
    const short* __restrict__ fastT, const short* __restrict__ xT,
    short* __restrict__ hebb_part)
{
    const int m0 = blockIdx.x * 256;
    const int n0 = blockIdx.y * 256;
    const size_t kb = (size_t)blockIdx.z * (B_SZ / SPLITK);
    gemm256_core<1>(&fastT[(size_t)m0 * B_SZ + kb], B_SZ,
                    &xT[(size_t)n0 * B_SZ + kb], B_SZ,
                    nullptr, hebb_part + (size_t)blockIdx.z * DOUT * DIN, m0, n0);
}

// ---------------- colsumsq from fastT (deterministic, no atomics) ----------------
__global__ __launch_bounds__(256) void colsumsq_kernel(const short* __restrict__ fastT,
                                                       float* __restrict__ sums) {
    const int m = blockIdx.x;
    const int tid = threadIdx.x;
    const short* row = &fastT[(size_t)m * B_SZ];
    float s = 0.f;
    for (int i = tid * 8; i < B_SZ; i += 256 * 8) {
        bf16x8 v = *(const bf16x8*)&row[i];
        #pragma unroll
        for (int j = 0; j < 8; ++j) { float f = bf2f(v[j]); s += f * f; }
    }
    __shared__ float red[256];
    red[tid] = s; __syncthreads();
    for (int off = 128; off > 0; off >>= 1) {
        if (tid < off) red[tid] += red[tid + off];
        __syncthreads();
    }
    if (tid == 0) sums[m] = red[0];
}

// ---------------- W_fast update with tanh epilogue ----------------
__global__ __launch_bounds__(256) void wfast_update(
    const float* __restrict__ Wf, const short* __restrict__ hebb_part,
    const float* __restrict__ colsumsq, const float* __restrict__ eff_lr,
    float* __restrict__ Wf_new)
{
    const int i0 = (blockIdx.x * 256 + threadIdx.x) * 8;
    const int m = i0 >> 10;
    const float lr = eff_lr[0];
    const float fgm = colsumsq[m] * (1.0f / (float)B_SZ);
    float h[8] = {0.f, 0.f, 0.f, 0.f, 0.f, 0.f, 0.f, 0.f};
    #pragma unroll
    for (int z = 0; z < SPLITK; ++z) {
        bf16x8 v = *(const bf16x8*)&hebb_part[(size_t)z * DOUT * DIN + i0];
        #pragma unroll
        for (int j = 0; j < 8; ++j) h[j] += bf2f(v[j]);
    }
    float4 w0 = *(const float4*)&Wf[i0];
    float4 w1 = *(const float4*)&Wf[i0 + 4];
    float w[8] = {w0.x, w0.y, w0.z, w0.w, w1.x, w1.y, w1.z, w1.w};
    float o[8];
    #pragma unroll
    for (int j = 0; j < 8; ++j)
        o[j] = w[j] + tanhf(h[j] * (1.0f / (float)B_SZ) - fgm * w[j]) * lr;
    *(float4*)&Wf_new[i0]     = make_float4(o[0], o[1], o[2], o[3]);
    *(float4*)&Wf_new[i0 + 4] = make_float4(o[4], o[5], o[6], o[7]);
}

// ---------------- combine + LayerNorm (in-place over fast) ----------------
__global__ __launch_bounds__(256) void ln_kernel(
    const float* __restrict__ slow, float* __restrict__ io,
    const float* __restrict__ gamma, const float* __restrict__ beta,
    const float* __restrict__ alpha)
{
    const int row = blockIdx.x;
    const int tid = threadIdx.x;
    const float a = alpha[0];
    const size_t base = (size_t)row * DOUT;
    float c[4];
    float s = 0.f, ss = 0.f;
    #pragma unroll
    for (int i = 0; i < 4; ++i) {
        int col = tid + i * 256;
        float v = slow[base + col] + a * io[base + col];
        c[i] = v; s += v; ss += v * v;
    }
    #pragma unroll
    for (int off = 32; off > 0; off >>= 1) {
        s  += __shfl_down(s, off);
        ss += __shfl_down(ss, off);
    }
    __shared__ float rs[4], rss[4];
    int wave = tid >> 6;
    if ((tid & 63) == 0) { rs[wave] = s; rss[wave] = ss; }
    __syncthreads();
    float S  = rs[0] + rs[1] + rs[2] + rs[3];
    float SS = rss[0] + rss[1] + rss[2] + rss[3];
    float mu = S * (1.0f / DOUT);
    float var = SS * (1.0f / DOUT) - mu * mu;
    float inv = rsqrtf(var + 1e-5f);
    #pragma unroll
    for (int i = 0; i < 4; ++i) {
        int col = tid + i * 256;
        io[base + col] = (c[i] - mu) * inv * gamma[col] + beta[col];
    }
}

extern "C" void kernel_launch(void* const* d_in, const int* in_sizes, int n_in,
                              void* d_out, int out_size, void* d_ws, size_t ws_size,
                              hipStream_t stream)
{
    const float* x     = (const float*)d_in[0];
    const float* plast = (const float*)d_in[1];
    const float* alpha = (const float*)d_in[2];
    const float* Wslow = (const float*)d_in[3];
    const float* Wfast = (const float*)d_in[4];
    const float* gamma = (const float*)d_in[5];
    const float* beta  = (const float*)d_in[6];

    float* out   = (float*)d_out;                 // [B, DOUT]; holds fast until LN
    float* slow  = out + (size_t)B_SZ * DOUT;     // [B, DOUT]
    float* wfnew = slow + (size_t)B_SZ * DOUT;    // [DOUT, DIN]

    // workspace layout (region A reused: xb until dual_gemm done, then fastT)
    char* ws = (char*)d_ws;
    const size_t SZ_XB   = (size_t)B_SZ * DIN * 2;           // 32 MB
    const size_t SZ_XT   = (size_t)DIN * B_SZ * 2;           // 32 MB
    const size_t SZ_WCAT = (size_t)2048 * DIN * 2;           // 4 MB
    const size_t SZ_HEBB = (size_t)SPLITK * DOUT * DIN * 2;  // 32 MB
    short* xb    = (short*)ws;
    short* fastT = xb;                                       // alias (xb dead after dual_gemm8)
    short* xT    = (short*)(ws + SZ_XB);
    short* wcat  = (short*)(ws + SZ_XB + SZ_XT);
    short* hebb  = (short*)(ws + SZ_XB + SZ_XT + SZ_WCAT);
    float* csq   = (float*)(ws + SZ_XB + SZ_XT + SZ_WCAT + SZ_HEBB);
    float* efflr = csq + DOUT;

    x_convert<<<dim3(B_SZ / 64, DIN / 64), 256, 0, stream>>>(x, xb, xT);
    convert_w2<<<(2 * DOUT * DIN / 4) / 256, 256, 0, stream>>>(Wslow, Wfast, wcat);
    init_kernel<<<1, 256, 0, stream>>>(plast, efflr, csq);
    dual_gemm8<<<512, 512, 0, stream>>>(xb, wcat, slow, out);
    fast_trans<<<dim3(B_SZ / 64, DOUT / 64), 256, 0, stream>>>(out, fastT);
    colsumsq_kernel<<<DOUT, 256, 0, stream>>>(fastT, csq);
    hebb_gemm8<<<dim3(DOUT / 256, DIN / 256, SPLITK), 512, 0, stream>>>(fastT, xT, hebb);
    wfast_update<<<(DOUT * DIN) / (256 * 8), 256, 0, stream>>>(Wfast, hebb, csq, efflr, wfnew);
    ln_kernel<<<B_SZ, 256, 0, stream>>>(slow, out, gamma, beta, alpha);
}

// Round 8
// 396.697 us; speedup vs baseline: 1.1388x; 1.0023x over previous
//
#include <hip/hip_runtime.h>
#include <cstdint>
#include <cstddef>

#define B_SZ 16384
#define DIN  1024
#define DOUT 1024
#define SPLITK 16

typedef short bf16x8 __attribute__((ext_vector_type(8)));
typedef float f32x4  __attribute__((ext_vector_type(4)));

static __device__ __forceinline__ short f2bf(float f) {
    union { float f; unsigned u; } v; v.f = f;
    unsigned r = v.u + 0x7fffu + ((v.u >> 16) & 1u);
    return (short)(r >> 16);
}
static __device__ __forceinline__ float bf2f(short s) {
    union { unsigned u; float f; } v; v.u = ((unsigned)(unsigned short)s) << 16;
    return v.f;
}
// async global->LDS, 16B per lane; LDS dest is wave-uniform base + lane*16 (linear)
static __device__ __forceinline__ void gload_lds16(const short* g, short* l) {
    __builtin_amdgcn_global_load_lds(
        (const __attribute__((address_space(1))) void*)g,
        (__attribute__((address_space(3))) void*)l, 16, 0, 0);
}

// ---------------- both weights fp32 -> bf16 into wcat [2048,1024] ----------------
__global__ __launch_bounds__(256) void convert_w2(const float* __restrict__ wsl,
                                                  const float* __restrict__ wfa,
                                                  short* __restrict__ out) {
    const int half = DOUT * DIN / 4;
    int i = blockIdx.x * 256 + threadIdx.x;
    const float* src = (i < half) ? wsl : wfa;
    int j = (i < half) ? i : i - half;
    float4 v = ((const float4*)src)[j];
    short4 o;
    o.x = f2bf(v.x); o.y = f2bf(v.y); o.z = f2bf(v.z); o.w = f2bf(v.w);
    ((short4*)out)[i] = o;
}

// ---------------- x: fp32 [B,DIN] -> xb bf16 [B,DIN] + xT bf16 [DIN,B] ----------------
__global__ __launch_bounds__(256) void x_convert(const float* __restrict__ x,
                                                 short* __restrict__ xb,
                                                 short* __restrict__ xT) {
    __shared__ short t[64 * 72];
    const int b0 = blockIdx.x * 64;
    const int d0 = blockIdx.y * 64;
    const int tid = threadIdx.x;
    const int r = tid >> 2;            // batch row 0..63
    const int c = (tid & 3) * 16;      // col seg
    short loc[16];
    #pragma unroll
    for (int i = 0; i < 4; ++i) {
        float4 v = *(const float4*)&x[(size_t)(b0 + r) * DIN + d0 + c + i * 4];
        loc[i * 4 + 0] = f2bf(v.x); loc[i * 4 + 1] = f2bf(v.y);
        loc[i * 4 + 2] = f2bf(v.z); loc[i * 4 + 3] = f2bf(v.w);
    }
    *(bf16x8*)&xb[(size_t)(b0 + r) * DIN + d0 + c]     = *(bf16x8*)&loc[0];
    *(bf16x8*)&xb[(size_t)(b0 + r) * DIN + d0 + c + 8] = *(bf16x8*)&loc[8];
    #pragma unroll
    for (int i = 0; i < 16; ++i) t[(c + i) * 72 + r] = loc[i];
    __syncthreads();
    const int d = tid >> 2, bs = (tid & 3) * 16;
    *(bf16x8*)&xT[(size_t)(d0 + d) * B_SZ + b0 + bs]     = *(bf16x8*)&t[d * 72 + bs];
    *(bf16x8*)&xT[(size_t)(d0 + d) * B_SZ + b0 + bs + 8] = *(bf16x8*)&t[d * 72 + bs + 8];
}

// ---------------- fastb bf16 [B,DOUT] -> fastT bf16 [DOUT,B] + csq atomics ----------------
__global__ __launch_bounds__(256) void ft_cs(const short* __restrict__ fastb,
                                             short* __restrict__ fastT,
                                             float* __restrict__ csq) {
    __shared__ short t[64 * 72];
    const int b0 = blockIdx.x * 64;
    const int d0 = blockIdx.y * 64;
    const int tid = threadIdx.x;
    const int r = tid >> 2;            // b row 0..63
    const int c = (tid & 3) * 16;      // d seg
    bf16x8 v0 = *(const bf16x8*)&fastb[(size_t)(b0 + r) * DOUT + d0 + c];
    bf16x8 v1 = *(const bf16x8*)&fastb[(size_t)(b0 + r) * DOUT + d0 + c + 8];
    #pragma unroll
    for (int i = 0; i < 8; ++i) { t[(c + i) * 72 + r] = v0[i]; t[(c + 8 + i) * 72 + r] = v1[i]; }
    __syncthreads();
    const int d = tid >> 2, bs = (tid & 3) * 16;
    bf16x8 o0 = *(const bf16x8*)&t[d * 72 + bs];
    bf16x8 o1 = *(const bf16x8*)&t[d * 72 + bs + 8];
    *(bf16x8*)&fastT[(size_t)(d0 + d) * B_SZ + b0 + bs]     = o0;
    *(bf16x8*)&fastT[(size_t)(d0 + d) * B_SZ + b0 + bs + 8] = o1;
    // column sum-of-squares: each thread holds 16 b-values of column d0+d
    float p = 0.f;
    #pragma unroll
    for (int i = 0; i < 8; ++i) { float a = bf2f(o0[i]), b = bf2f(o1[i]); p += a * a + b * b; }
    p += __shfl_down(p, 2);
    p += __shfl_down(p, 1);
    if ((tid & 3) == 0) atomicAdd(&csq[d0 + d], p);
}

// ---------------- init: eff_lr + zero csq ----------------
__global__ __launch_bounds__(256) void init_kernel(const float* __restrict__ plast,
                                                   float* __restrict__ eff_lr,
                                                   float* __restrict__ csq) {
    int tid = threadIdx.x;
    for (int i = tid; i < DOUT; i += 256) csq[i] = 0.f;
    float s = 0.f;
    for (int i = tid; i < B_SZ; i += 256) s += plast[i];
    __shared__ float red[256];
    red[tid] = s; __syncthreads();
    for (int off = 128; off > 0; off >>= 1) {
        if (tid < off) red[tid] += red[tid + off];
        __syncthreads();
    }
    if (tid == 0) eff_lr[0] = (red[0] / (float)B_SZ) * 0.1f;
}

// ================= 256x256 8-phase GEMM core (m201 template, plain HIP) =================
// C = A @ B^T. A row-major [M,K] (ld=lda), B row-major [N,K] (ld=ldb). K per call = 1024
// (NT=16 K-tiles of 64). 8 waves (2M x 4N), 128 KiB LDS (declared by CALLER and passed
// in, so multiple template instantiations in one kernel share one LDS block).
// LDS swizzle (G4, 128B-row tiles): 16B-slot index XORed with (row&7), same involution on
// staging global source (linear gload_lds dest) and ds_read. vmcnt(4) only at phases 4/8.
#define PRIO1 __builtin_amdgcn_s_setprio(1)
#define PRIO0 __builtin_amdgcn_s_setprio(0)
#define BARX  asm volatile("s_barrier" ::: "memory")
#define LGKM0 asm volatile("s_waitcnt lgkmcnt(0)" ::: "memory")
#define VMC4  asm volatile("s_waitcnt vmcnt(4)" ::: "memory")
#define VMC0  asm volatile("s_waitcnt vmcnt(0)" ::: "memory")

#define STG(RO, SRC, LD, KT, H) do { \
    const short* _s = (SRC) + (size_t)((H) * 128 + srow) * (LD) + (KT) * 64 + scol; \
    gload_lds16(_s, &L[(RO) + ((H) * 128 + wrow8) * 64]); \
    gload_lds16(_s + (size_t)64 * (LD), &L[(RO) + ((H) * 128 + 64 + wrow8) * 64]); \
} while (0)

#define RDA(RO, MH) do { \
    const int _rb = (RO) + (wm * 128 + (MH) * 64 + l16) * 64; \
    _Pragma("unroll") for (int mf = 0; mf < 4; ++mf) { \
        a_[mf][0] = *(const bf16x8*)&L[_rb + mf * 1024 + c0]; \
        a_[mf][1] = *(const bf16x8*)&L[_rb + mf * 1024 + (c0 ^ 32)]; \
    } \
} while (0)

#define RDB(RO, NH) do { \
    const int _rb = (RO) + (wn * 64 + (NH) * 32 + l16) * 64; \
    _Pragma("unroll") for (int nf = 0; nf < 2; ++nf) { \
        b_[NH][nf][0] = *(const bf16x8*)&L[_rb + nf * 1024 + c0]; \
        b_[NH][nf][1] = *(const bf16x8*)&L[_rb + nf * 1024 + (c0 ^ 32)]; \
    } \
} while (0)

#define MM(MH, NH) do { \
    _Pragma("unroll") for (int mf = 0; mf < 4; ++mf) \
    _Pragma("unroll") for (int nf = 0; nf < 2; ++nf) { \
        acc[(MH)*4+mf][(NH)*2+nf] = __builtin_amdgcn_mfma_f32_16x16x32_bf16(a_[mf][0], b_[NH][nf][0], acc[(MH)*4+mf][(NH)*2+nf], 0, 0, 0); \
        acc[(MH)*4+mf][(NH)*2+nf] = __builtin_amdgcn_mfma_f32_16x16x32_bf16(a_[mf][1], b_[NH][nf][1], acc[(MH)*4+mf][(NH)*2+nf], 0, 0, 0); \
    } \
} while (0)

template<int EPI>
static __device__ __forceinline__ void gemm256_core(
    short* L,                                  // caller-provided 128 KiB LDS
    const short* __restrict__ Asrc, int lda,   // at [m0, k0]
    const short* __restrict__ Bsrc, int ldb,   // at [n0, k0]
    float* __restrict__ dstf,                  // EPI=0: fp32 out base [*,1024]
    short* __restrict__ dsth,                  // EPI=1: bf16 out base [*,DIN]
    int m0, int cb)
{
    const int A0o = 0, A1o = 16384, B0o = 32768, B1o = 49152;
    const int tid  = threadIdx.x;
    const int lane = tid & 63;
    const int w    = tid >> 6;           // 0..7
    const int wm   = w >> 2;             // 0..1
    const int wn   = w & 3;              // 0..3
    const int quad = lane >> 4;
    const int l16  = lane & 15;
    const int c0   = ((quad ^ (l16 & 7)) << 3);             // swizzled 16B-slot (shorts)
    const int wrow8 = w * 8;
    const int srow  = tid >> 3;                             // staging row 0..63
    const int scol  = (((lane & 7) ^ (lane >> 3)) << 3);    // pre-swizzled src col

    f32x4 acc[8][4] = {};
    bf16x8 a_[4][2];
    bf16x8 b_[2][2][2];

    // prologue: tile0 -> buf0 (B,A), tile1 B -> buf1; wait all but last 4, barrier
    STG(B0o, Bsrc, ldb, 0, 0); STG(B0o, Bsrc, ldb, 0, 1);
    STG(A0o, Asrc, lda, 0, 0); STG(A0o, Asrc, lda, 0, 1);
    STG(B1o, Bsrc, ldb, 1, 0); STG(B1o, Bsrc, ldb, 1, 1);
    VMC4; BARX;

    for (int it = 0; it < 7; ++it) {
        const int t = 2 * it;
        // ---- group 1: compute buf0 (tile t) ----
        RDA(A0o, 0); RDB(B0o, 0); STG(A1o, Asrc, lda, t + 1, 0);
        BARX; LGKM0; PRIO1; MM(0, 0); PRIO0; BARX;
        RDB(B0o, 1); STG(A1o, Asrc, lda, t + 1, 1);
        BARX; LGKM0; PRIO1; MM(0, 1); PRIO0; BARX;
        RDA(A0o, 1); STG(B0o, Bsrc, ldb, t + 2, 0);
        BARX; LGKM0; PRIO1; MM(1, 1); PRIO0; BARX;
        STG(B0o, Bsrc, ldb, t + 2, 1);
        BARX; PRIO1; MM(1, 0); PRIO0; VMC4; BARX;
        // ---- group 2: compute buf1 (tile t+1) ----
        RDA(A1o, 0); RDB(B1o, 0); STG(A0o, Asrc, lda, t + 2, 0);
        BARX; LGKM0; PRIO1; MM(0, 0); PRIO0; BARX;
        RDB(B1o, 1); STG(A0o, Asrc, lda, t + 2, 1);
        BARX; LGKM0; PRIO1; MM(0, 1); PRIO0; BARX;
        RDA(A1o, 1); STG(B1o, Bsrc, ldb, t + 3, 0);
        BARX; LGKM0; PRIO1; MM(1, 1); PRIO0; BARX;
        STG(B1o, Bsrc, ldb, t + 3, 1);
        BARX; PRIO1; MM(1, 0); PRIO0; VMC4; BARX;
    }
    // ---- last iteration (tiles 14,15) ----
    // A1<-15 staged here (ring stages A1 just-in-time); VMC0 drains it + in-flight
    // B1<-15 before group 2 reads buf1.
    RDA(A0o, 0); RDB(B0o, 0); STG(A1o, Asrc, lda, 15, 0);
    BARX; LGKM0; PRIO1; MM(0, 0); PRIO0; BARX;
    RDB(B0o, 1); STG(A1o, Asrc, lda, 15, 1);
    BARX; LGKM0; PRIO1; MM(0, 1); PRIO0; BARX;
    RDA(A0o, 1);
    BARX; LGKM0; PRIO1; MM(1, 1); PRIO0; BARX;
    BARX; PRIO1; MM(1, 0); PRIO0; VMC0; BARX;
    RDA(A1o, 0); RDB(B1o, 0);
    BARX; LGKM0; PRIO1; MM(0, 0); PRIO0; BARX;
    RDB(B1o, 1);
    BARX; LGKM0; PRIO1; MM(0, 1); PRIO0; BARX;
    RDA(A1o, 1);
    BARX; LGKM0; PRIO1; MM(1, 1); PRIO0; BARX;
    PRIO1; MM(1, 0); PRIO0;

    // ---- epilogue ----
    if (EPI == 0) {
        #pragma unroll
        for (int mf = 0; mf < 8; ++mf) {
            const int r0 = m0 + wm * 128 + mf * 16 + quad * 4;
            #pragma unroll
            for (int nf = 0; nf < 4; ++nf) {
                const int cc = cb + wn * 64 + nf * 16 + l16;
                #pragma unroll
                for (int r = 0; r < 4; ++r)
                    dstf[(size_t)(r0 + r) * 1024 + cc] = acc[mf][nf][r];
            }
        }
    } else {
        #pragma unroll
        for (int mf = 0; mf < 8; ++mf) {
            const int r0 = m0 + wm * 128 + mf * 16 + quad * 4;
            #pragma unroll
            for (int nf = 0; nf < 4; ++nf) {
                const int cc = cb + wn * 64 + nf * 16 + l16;
                #pragma unroll
                for (int r = 0; r < 4; ++r)
                    dsth[(size_t)(r0 + r) * DIN + cc] = f2bf(acc[mf][nf][r]);
            }
        }
    }
}

// dual GEMM: [16384,2048] = xb @ wcat^T; grid 512 (64 m x 8 n), XCD-swizzled.
// Slow half (panels 0-3) -> slow fp32 [B,1024]; fast half (panels 4-7) -> fastb bf16
// [B,1024] (reuses the verified EPI=1 epilogue; ld = DIN = 1024).
__global__ __launch_bounds__(512) void dual_gemm8(
    const short* __restrict__ Xb, const short* __restrict__ Wc,
    float* __restrict__ slow_out, short* __restrict__ fastb)
{
    __shared__ short L[65536];   // single 128 KiB block shared by both core instantiations
    const int bid = blockIdx.x;                    // 512 blocks, 512 % 8 == 0
    const int id  = (bid & 7) * 64 + (bid >> 3);   // bijective XCD swizzle
    const int bm  = id & 63, bn = id >> 6;         // XCD owns one W-panel column
    const int m0  = bm * 256, n0 = bn * 256;
    if (n0 < 1024)
        gemm256_core<0>(L, &Xb[(size_t)m0 * DIN], DIN, &Wc[(size_t)n0 * DIN], DIN,
                        slow_out, nullptr, m0, n0);
    else
        gemm256_core<1>(L, &Xb[(size_t)m0 * DIN], DIN, &Wc[(size_t)n0 * DIN], DIN,
                        nullptr, fastb, m0, n0 - 1024);
}

// hebb GEMM: hebb_part[z] = fastT[:,zK:] @ xT[:,zK:]^T; 256 blocks, XCD-chunked so each
// XCD's 32 resident blocks cover 2 K-slices whose 4 A + 4 B panels (4 MB) fit its L2.
__global__ __launch_bounds__(512) void hebb_gemm8(
    const short* __restrict__ fastT, const short* __restrict__ xT,
    short* __restrict__ hebb_part)
{
    __shared__ short L[65536];
    const int bid = blockIdx.x;                    // 0..255, 256 % 8 == 0
    const int id  = (bid & 7) * 32 + (bid >> 3);   // bijective XCD chunking
    const int z   = id >> 4;                       // K-slice 0..15
    const int mn  = id & 15;
    const int m0  = (mn >> 2) * 256;
    const int n0  = (mn & 3) * 256;
    const size_t kb = (size_t)z * (B_SZ / SPLITK);
    gemm256_core<1>(L, &fastT[(size_t)m0 * B_SZ + kb], B_SZ,
                    &xT[(size_t)n0 * B_SZ + kb], B_SZ,
                    nullptr, hebb_part + (size_t)z * DOUT * DIN, m0, n0);
}

// ---------------- W_fast update with tanh epilogue ----------------
__global__ __launch_bounds__(256) void wfast_update(
    const float* __restrict__ Wf, const short* __restrict__ hebb_part,
    const float* __restrict__ colsumsq, const float* __restrict__ eff_lr,
    float* __restrict__ Wf_new)
{
    const int i0 = (blockIdx.x * 256 + threadIdx.x) * 8;
    const int m = i0 >> 10;
    const float lr = eff_lr[0];
    const float fgm = colsumsq[m] * (1.0f / (float)B_SZ);
    float h[8] = {0.f, 0.f, 0.f, 0.f, 0.f, 0.f, 0.f, 0.f};
    #pragma unroll
    for (int z = 0; z < SPLITK; ++z) {
        bf16x8 v = *(const bf16x8*)&hebb_part[(size_t)z * DOUT * DIN + i0];
        #pragma unroll
        for (int j = 0; j < 8; ++j) h[j] += bf2f(v[j]);
    }
    float4 w0 = *(const float4*)&Wf[i0];
    float4 w1 = *(const float4*)&Wf[i0 + 4];
    float w[8] = {w0.x, w0.y, w0.z, w0.w, w1.x, w1.y, w1.z, w1.w};
    float o[8];
    #pragma unroll
    for (int j = 0; j < 8; ++j)
        o[j] = w[j] + tanhf(h[j] * (1.0f / (float)B_SZ) - fgm * w[j]) * lr;
    *(float4*)&Wf_new[i0]     = make_float4(o[0], o[1], o[2], o[3]);
    *(float4*)&Wf_new[i0 + 4] = make_float4(o[4], o[5], o[6], o[7]);
}

// ---------------- combine (slow fp32 + alpha * fastb bf16) + LayerNorm -> out ----------
__global__ __launch_bounds__(256) void ln2_kernel(
    const float* __restrict__ slow, const short* __restrict__ fastb,
    float* __restrict__ out,
    const float* __restrict__ gamma, const float* __restrict__ beta,
    const float* __restrict__ alpha)
{
    const int row = blockIdx.x;
    const int tid = threadIdx.x;
    const float a = alpha[0];
    const size_t base = (size_t)row * DOUT;
    float c[4];
    float s = 0.f, ss = 0.f;
    #pragma unroll
    for (int i = 0; i < 4; ++i) {
        int col = tid + i * 256;
        float v = slow[base + col] + a * bf2f(fastb[base + col]);
        c[i] = v; s += v; ss += v * v;
    }
    #pragma unroll
    for (int off = 32; off > 0; off >>= 1) {
        s  += __shfl_down(s, off);
        ss += __shfl_down(ss, off);
    }
    __shared__ float rs[4], rss[4];
    int wave = tid >> 6;
    if ((tid & 63) == 0) { rs[wave] = s; rss[wave] = ss; }
    __syncthreads();
    float S  = rs[0] + rs[1] + rs[2] + rs[3];
    float SS = rss[0] + rss[1] + rss[2] + rss[3];
    float mu = S * (1.0f / DOUT);
    float var = SS * (1.0f / DOUT) - mu * mu;
    float inv = rsqrtf(var + 1e-5f);
    #pragma unroll
    for (int i = 0; i < 4; ++i) {
        int col = tid + i * 256;
        out[base + col] = (c[i] - mu) * inv * gamma[col] + beta[col];
    }
}

extern "C" void kernel_launch(void* const* d_in, const int* in_sizes, int n_in,
                              void* d_out, int out_size, void* d_ws, size_t ws_size,
                              hipStream_t stream)
{
    const float* x     = (const float*)d_in[0];
    const float* plast = (const float*)d_in[1];
    const float* alpha = (const float*)d_in[2];
    const float* Wslow = (const float*)d_in[3];
    const float* Wfast = (const float*)d_in[4];
    const float* gamma = (const float*)d_in[5];
    const float* beta  = (const float*)d_in[6];

    float* out   = (float*)d_out;                 // [B, DOUT]
    float* slow  = out + (size_t)B_SZ * DOUT;     // [B, DOUT]
    float* wfnew = slow + (size_t)B_SZ * DOUT;    // [DOUT, DIN]

    // workspace layout; region reuse via disjoint lifetimes:
    //   xb [dual] -> fastT [ft_cs..hebb]     (alias)
    //   fastb [dual..ln2] -> hebb partials [hebb..wfast]  (alias, ln2 runs BEFORE hebb)
    char* ws = (char*)d_ws;
    const size_t SZ_XB   = (size_t)B_SZ * DIN * 2;           // 32 MB
    const size_t SZ_XT   = (size_t)DIN * B_SZ * 2;           // 32 MB
    const size_t SZ_WCAT = (size_t)2048 * DIN * 2;           // 4 MB
    const size_t SZ_HEBB = (size_t)SPLITK * DOUT * DIN * 2;  // 32 MB (== fastb 32 MB)
    short* xb    = (short*)ws;
    short* fastT = xb;                                       // alias
    short* xT    = (short*)(ws + SZ_XB);
    short* wcat  = (short*)(ws + SZ_XB + SZ_XT);
    short* fastb = (short*)(ws + SZ_XB + SZ_XT + SZ_WCAT);   // alias w/ hebb
    short* hebb  = fastb;
    float* csq   = (float*)(ws + SZ_XB + SZ_XT + SZ_WCAT + SZ_HEBB);
    float* efflr = csq + DOUT;

    x_convert<<<dim3(B_SZ / 64, DIN / 64), 256, 0, stream>>>(x, xb, xT);
    convert_w2<<<(2 * DOUT * DIN / 4) / 256, 256, 0, stream>>>(Wslow, Wfast, wcat);
    init_kernel<<<1, 256, 0, stream>>>(plast, efflr, csq);
    dual_gemm8<<<512, 512, 0, stream>>>(xb, wcat, slow, fastb);
    ft_cs<<<dim3(B_SZ / 64, DOUT / 64), 256, 0, stream>>>(fastb, fastT, csq);
    ln2_kernel<<<B_SZ, 256, 0, stream>>>(slow, fastb, out, gamma, beta, alpha);
    hebb_gemm8<<<256, 512, 0, stream>>>(fastT, xT, hebb);   // overwrites fastb (ln2 done)
    wfast_update<<<(DOUT * DIN) / (256 * 8), 256, 0, stream>>>(Wfast, hebb, csq, efflr, wfnew);
}